// Round 8
// baseline (191.340 us; speedup 1.0000x reference)
//
#include <hip/hip_runtime.h>
#include <stdint.h>

#define DI __device__ __forceinline__

typedef __attribute__((ext_vector_type(8))) short short8;
typedef __attribute__((ext_vector_type(8))) __bf16 bf16x8;
typedef __attribute__((ext_vector_type(2))) __bf16 bf16x2;
typedef __attribute__((ext_vector_type(4))) float f32x4;
typedef unsigned short u16;

static constexpr int SEQ = 2048;
static constexpr int EMB = 1024;

// round-to-nearest-even fp32 -> bf16
DI u16 f2bf(float x) {
  uint32_t u = __float_as_uint(x);
  u += 0x7fffu + ((u >> 16) & 1u);
  return (u16)(u >> 16);
}

DI uint32_t pkbf(float a, float b) {
#if __has_builtin(__builtin_amdgcn_cvt_pk_bf16_f32)
  bf16x2 v = __builtin_amdgcn_cvt_pk_bf16_f32(a, b);
  return __builtin_bit_cast(uint32_t, v);
#else
  return (uint32_t)f2bf(a) | ((uint32_t)f2bf(b) << 16);
#endif
}

DI float fexp2(float x) {
#if __has_builtin(__builtin_amdgcn_exp2f)
  return __builtin_amdgcn_exp2f(x);
#else
  return exp2f(x);
#endif
}

DI f32x4 mfma16(short8 a, short8 b, f32x4 c) {
  return __builtin_amdgcn_mfma_f32_16x16x32_bf16(
      __builtin_bit_cast(bf16x8, a), __builtin_bit_cast(bf16x8, b), c, 0, 0, 0);
}

// async global->LDS, 16B per lane; LDS dest = wave-uniform base + lane*16
DI void g2l16(const u16* g, u16* l) {
  __builtin_amdgcn_global_load_lds(
      (const __attribute__((address_space(1))) unsigned int*)g,
      (__attribute__((address_space(3))) unsigned int*)l, 16, 0, 0);
}

// s_waitcnt imms: vm bits[3:0]+[15:14], exp [6:4], lgkm [11:8]
DI void wait_vm0() { __builtin_amdgcn_s_waitcnt(0x0F70); }   // vmcnt(0) only
DI void wait_vm6() { __builtin_amdgcn_s_waitcnt(0x0F76); }   // vmcnt(6) only
DI void wait_lgkm0() { __builtin_amdgcn_s_waitcnt(0xC07F); } // lgkmcnt(0) only
DI void memfence_c() { asm volatile("" ::: "memory"); }      // compiler-only fence

// ---------------- fused fp32 -> bf16 conversion (all 5 tensors) ----------------
__global__ __launch_bounds__(256) void cvt_all(
    const float* __restrict__ x,  const float* __restrict__ wq,
    const float* __restrict__ wk, const float* __restrict__ wv,
    const float* __restrict__ wo,
    u16* __restrict__ xb, u16* __restrict__ wqb, u16* __restrict__ wkb,
    u16* __restrict__ wvb, u16* __restrict__ wob) {
  const int bx = blockIdx.x;
  const float* s; u16* d; int off;
  if (bx < 4096) { s = x; d = xb; off = bx << 8; }
  else {
    const int r = bx - 4096, wsel = r >> 10;
    off = (r & 1023) << 8;
    s = wsel == 0 ? wq : (wsel == 1 ? wk : (wsel == 2 ? wv : wo));
    d = wsel == 0 ? wqb : (wsel == 1 ? wkb : (wsel == 2 ? wvb : wob));
  }
  const int i = off + threadIdx.x;
  float4 v = ((const float4*)s)[i];
  uint2 o;
  o.x = pkbf(v.x, v.y);
  o.y = pkbf(v.z, v.w);
  ((uint2*)d)[i] = o;
}

// ------- double-buffered GEMM K-loop, BK=32 (used by gemm_out) --------------
template <int NB>   // b-subtiles per wave: 4 -> BN=128, 2 -> BN=64
DI void gemm_core_db(const u16* __restrict__ A, const u16* __restrict__ B,
                     int m0, int n0, u16* Al, u16* Bl, f32x4 (&acc)[4][NB],
                     int t) {
  const int L = t & 63, w = t >> 6;
  const int wm = (w >> 1) * 64, wn = (w & 1) * (NB * 16);
  const int r = L & 15, g = L >> 4;
  const int gofs = (g ^ ((L >> 1) & 3)) * 8;
  const int scol = (((t & 3) ^ ((t >> 3) & 3)) * 8);
  const int arow0 = t >> 2, arow1 = (t + 256) >> 2;
  const u16* Ap0 = A + ((size_t)(m0 + arow0) << 10) + scol;
  const u16* Ap1 = A + ((size_t)(m0 + arow1) << 10) + scol;
  const u16* Bp0 = B + ((size_t)(n0 + arow0) << 10) + scol;
  const u16* Bp1 = B + ((size_t)(n0 + arow1) << 10) + scol;
  constexpr int AH = 128 * 32;      // elems per A half
  constexpr int BH = NB * 32 * 32;  // elems per B half

  // prologue: stage tile 0 into half 0
  g2l16(Ap0, Al + t * 8);
  g2l16(Ap1, Al + (t + 256) * 8);
  g2l16(Bp0, Bl + t * 8);
  if (NB == 4) g2l16(Bp1, Bl + (t + 256) * 8);
  wait_vm0();
  __syncthreads();

  for (int ks = 0; ks < 32; ++ks) {
    const int cur = ks & 1;
    const u16* Alc = Al + cur * AH;
    const u16* Blc = Bl + cur * BH;
    if (ks < 31) {                        // prefetch tile ks+1 (async, no wait)
      const int k0 = (ks + 1) * 32;
      u16* Aln = Al + (cur ^ 1) * AH;
      u16* Bln = Bl + (cur ^ 1) * BH;
      g2l16(Ap0 + k0, Aln + t * 8);
      g2l16(Ap1 + k0, Aln + (t + 256) * 8);
      g2l16(Bp0 + k0, Bln + t * 8);
      if (NB == 4) g2l16(Bp1 + k0, Bln + (t + 256) * 8);
    }
    short8 af[4], bfr[NB];
#pragma unroll
    for (int mt = 0; mt < 4; ++mt)
      af[mt] = *(const short8*)(Alc + (wm + mt * 16 + r) * 32 + gofs);
#pragma unroll
    for (int nt = 0; nt < NB; ++nt)
      bfr[nt] = *(const short8*)(Blc + (wn + nt * 16 + r) * 32 + gofs);
#pragma unroll
    for (int mt = 0; mt < 4; ++mt)
#pragma unroll
      for (int nt = 0; nt < NB; ++nt)
        acc[mt][nt] = mfma16(af[mt], bfr[nt], acc[mt][nt]);
    if (ks < 31) {
      wait_vm0();                         // prefetch landed (after compute!)
      __syncthreads();                    // one barrier per iter
    }
  }
}

// ---------------- fused QKV projection: 8-phase 256x256 schedule -------------
// (verified round 5) C[4096 x 3072] = xb * W^T, K=1024. 192 blocks, 512 thr
// (8 waves = 2M x 4N), per-wave 128x64. BK=64. LDS 128 KB, XOR-8 swizzle.
// Counted vmcnt(6): 3 half-tiles stay in flight across raw s_barriers.
__global__ __launch_bounds__(512, 2) void gemm_qkv(
    const u16* __restrict__ xb,
    const u16* __restrict__ wqb, const u16* __restrict__ wkb,
    const u16* __restrict__ wvb,
    u16* __restrict__ Qb, u16* __restrict__ Kb, u16* __restrict__ Vt) {
  __shared__ u16 Al[2 * 256 * 64];      // 64 KB
  __shared__ u16 Bl[2 * 256 * 64];      // 64 KB
  const int t = threadIdx.x, L = t & 63, w = t >> 6;
  const int wm = (w >> 2) * 128, wn = (w & 3) * 64;
  const int r = L & 15, g = L >> 4;
  const int e = r & 7;
  const int ck0 = (g ^ e) * 8, ck1 = ((4 + g) ^ e) * 8;   // chunk for ks=0/1
  const int arow = wm >> 1;    // within-half j offset for A frag reads
  const int brow = wn >> 1;    // within-half j offset for B frag reads

  const int bx = blockIdx.x;
  const int m0 = (bx & 15) * 256;
  const int n0 = (bx >> 4) * 256;
  const int which = n0 >> 10;                 // 0:Q 1:K 2:V
  const u16* wsel = which == 0 ? wqb : (which == 1 ? wkb : wvb);
  const int nl0 = n0 & 1023;

  // staging constants: thread handles half-chunks c0=t (j 0..63), c1=t+512
  const int j0 = t >> 3, j1 = (t + 512) >> 3;
  const int sc0 = ((t & 7) ^ (j0 & 7)) * 8;
  const int sc1 = (((t + 512) & 7) ^ (j1 & 7)) * 8;
  const int ar0 = (j0 >> 6) * 128 + (j0 & 63);   // A half-0 row (h adds 64)
  const int ar1 = (j1 >> 6) * 128 + (j1 & 63);
  const int br0 = (j0 >> 5) * 64 + (j0 & 31);    // B half-0 row (h adds 32)
  const int br1 = (j1 >> 5) * 64 + (j1 & 31);
  const u16* As0 = xb + ((size_t)(m0 + ar0) << 10) + sc0;
  const u16* As1 = xb + ((size_t)(m0 + ar1) << 10) + sc1;
  const u16* Bs0 = wsel + ((size_t)(nl0 + br0) << 10) + sc0;
  const u16* Bs1 = wsel + ((size_t)(nl0 + br1) << 10) + sc1;

  f32x4 acc[8][4];
#pragma unroll
  for (int i = 0; i < 8; ++i)
#pragma unroll
    for (int j = 0; j < 4; ++j) acc[i][j] = f32x4{0.f, 0.f, 0.f, 0.f};
  short8 af[4][2], bn[4][2];

#define STG_A(kt, h)                                                          \
  { const size_t ko = (size_t)(kt) * 64 + (size_t)(h) * (64 << 10);           \
    u16* dd = Al + (((kt) & 1) << 14) + ((h) << 13);                          \
    g2l16(As0 + ko, dd + t * 8);                                              \
    g2l16(As1 + ko, dd + (t + 512) * 8); }
#define STG_B(kt, h)                                                          \
  { const size_t ko = (size_t)(kt) * 64 + (size_t)(h) * (32 << 10);           \
    u16* dd = Bl + (((kt) & 1) << 14) + ((h) << 13);                          \
    g2l16(Bs0 + ko, dd + t * 8);                                              \
    g2l16(Bs1 + ko, dd + (t + 512) * 8); }
#define LDA(bs, mh)                                                           \
  _Pragma("unroll") for (int mf = 0; mf < 4; ++mf) {                          \
    const u16* p = Al + ((bs) << 14) + ((mh) << 13) +                         \
                   (arow + mf * 16 + r) * 64;                                 \
    af[mf][0] = *(const short8*)(p + ck0);                                    \
    af[mf][1] = *(const short8*)(p + ck1); }
#define LDB(bs, nh)                                                           \
  _Pragma("unroll") for (int nf = 0; nf < 2; ++nf) {                          \
    const u16* p = Bl + ((bs) << 14) + ((nh) << 13) +                         \
                   (brow + nf * 16 + r) * 64;                                 \
    bn[(nh) * 2 + nf][0] = *(const short8*)(p + ck0);                         \
    bn[(nh) * 2 + nf][1] = *(const short8*)(p + ck1); }
#define MM(mh, nh)                                                            \
  _Pragma("unroll") for (int ks = 0; ks < 2; ++ks)                            \
  _Pragma("unroll") for (int mf = 0; mf < 4; ++mf)                            \
  _Pragma("unroll") for (int nf = 0; nf < 2; ++nf)                            \
    acc[(mh) * 4 + mf][(nh) * 2 + nf] = mfma16(                               \
        af[mf][ks], bn[(nh) * 2 + nf][ks], acc[(mh) * 4 + mf][(nh) * 2 + nf]);
#define PH_MID()                                                              \
  { memfence_c(); __builtin_amdgcn_s_barrier(); memfence_c();                 \
    wait_lgkm0(); __builtin_amdgcn_sched_barrier(0);                          \
    __builtin_amdgcn_s_setprio(1); }
#define PH_END()                                                              \
  { __builtin_amdgcn_s_setprio(0); __builtin_amdgcn_sched_barrier(0);         \
    memfence_c(); __builtin_amdgcn_s_barrier(); memfence_c(); }
// VMODE: 0 -> vmcnt(6), 1 -> vmcnt(0), 2 -> none
#define TILE(tt, S1, S2, VMODE)                                               \
  { const int bs_ = (tt) & 1;                                                 \
    LDA(bs_, 0); LDB(bs_, 0);                                                 \
    if (S1) STG_A((tt) + 1, 1);                                               \
    PH_MID(); MM(0, 0); PH_END();                                             \
    LDB(bs_, 1);                                                              \
    if (S2) STG_A((tt) + 2, 0);                                               \
    PH_MID(); MM(0, 1); PH_END();                                             \
    LDA(bs_, 1);                                                              \
    if (S2) STG_B((tt) + 2, 0);                                               \
    PH_MID(); MM(1, 1); PH_END();                                             \
    if (S2) STG_B((tt) + 2, 1);                                               \
    if ((VMODE) == 0) wait_vm6();                                             \
    else if ((VMODE) == 1) wait_vm0();                                        \
    PH_MID(); MM(1, 0); PH_END(); }

  // prologue: tiles 0 (all 4 halves) + tile 1 (3 halves); vmcnt(6) -> tile 0
  // fully landed (newest 3 halves may still be in flight)
  STG_A(0, 0); STG_B(0, 0); STG_B(0, 1); STG_A(0, 1);
  STG_A(1, 0); STG_B(1, 0); STG_B(1, 1);
  wait_vm6();
  memfence_c(); __builtin_amdgcn_s_barrier(); memfence_c();

  for (int tp = 0; tp < 7; ++tp) {      // tiles 0..13, buffer parity folded
    TILE(2 * tp, 1, 1, 0);
    TILE(2 * tp + 1, 1, 1, 0);
  }
  TILE(14, 1, 0, 1);                    // stage A-h1(15) only; drain vmcnt(0)
  TILE(15, 0, 0, 2);                    // no stages, no vmcnt

#undef STG_A
#undef STG_B
#undef LDA
#undef LDB
#undef MM
#undef PH_MID
#undef PH_END
#undef TILE

  // epilogue
  const int rl = (L >> 4) * 4, cl = L & 15;
  if (which < 2) {
    u16* outp = which == 0 ? Qb : Kb;
    // fold 1/sqrt(64) * log2(e) into Q (softmax runs in exp2 domain)
    const float sc = which == 0 ? 0.125f * 1.44269504089f : 1.0f;
#pragma unroll
    for (int mt = 0; mt < 8; ++mt) {
#pragma unroll
      for (int nt = 0; nt < 4; ++nt) {
        const int n = nl0 + wn + nt * 16 + cl;
#pragma unroll
        for (int rr = 0; rr < 4; ++rr) {
          const int m = m0 + wm + mt * 16 + rl + rr;
          outp[(size_t)m * EMB + n] = f2bf(acc[mt][nt][rr] * sc);
        }
      }
    }
  } else {
    // V: write transposed per head: Vt[(b*16+h)*64 + d][s]
#pragma unroll
    for (int mt = 0; mt < 8; ++mt) {
      const int mbase = m0 + wm + mt * 16 + rl;
      const int b = mbase >> 11, s = mbase & 2047;
#pragma unroll
      for (int nt = 0; nt < 4; ++nt) {
        const int n = nl0 + wn + nt * 16 + cl;
        const int h = n >> 6, d = n & 63;
        uint2 o;
        o.x = pkbf(acc[mt][nt][0], acc[mt][nt][1]);
        o.y = pkbf(acc[mt][nt][2], acc[mt][nt][3]);
        *(uint2*)(Vt + ((size_t)((b * 16 + h) * 64 + d) << 11) + s) = o;
      }
    }
  }
}

// ---------- flash attention (causal), in-block key-split, P in LDS ----------
// v8 = the R4/R5-verified per-wave code with: single-buffered K/V (LDS 64 KB
// -> 2 blocks/CU) and grid 512 one-job-per-block. Two barrier-independent
// blocks per CU: one block's MFMA/VALU covers the other's staging drain
// (the dbuf's job), so the double buffer is dropped for occupancy.
// Blocks {i, i+256} co-locate under round-robin dispatch (same XCD: (i+256)%8
// == i%8; same CU slot) and carry qt {15-base, base} -> 17 tiles per CU.
// Wave-group gid=w>>2 handles keys [kt*128+gid*64, +64); partial (O,l) are
// linear (exp2-domain softmax) -> one LDS combine at the end.
__global__ __launch_bounds__(512, 4) void attn(
    const u16* __restrict__ Qb, const u16* __restrict__ Kb,
    const u16* __restrict__ Vt, u16* __restrict__ Ob) {
  __shared__ __align__(16) u16 smem[32768];   // 64 KB -> 2 blocks/CU
  u16* Kl = smem;                             // [128 key][64 d]  XOR-8 (16 KB)
  u16* Vl = smem + 8192;                      // [64 d][128 key]  XOR-8 (16 KB)
  u16* Pl = smem + 16384;                     // [2 gid][128 q][64 key] (32 KB); Q staged in Pl[0]
  float* Oc = (float*)smem;                   // combine: [128][68] f32 (34816 B, over dead K/V/P-head)
  float* Lc = (float*)(smem + 17408);         // 128 f32 @ byte 34816 (dead P region)

  const int t = threadIdx.x, w = t >> 6, gid = w >> 2, wl = w & 3;
  const int L = t & 63, g = L >> 4, cl = L & 15;
  const int gk = g ^ (cl & 3);          // swizzled low chunk bits for frag reads
  const int khi = (cl >> 2) & 1;        // swizzled high chunk bit
  const int qrow = wl * 16 + cl;

  // decode: grp selects qt half; slot -> XCD-contiguous (bh, base)
  const int idx = blockIdx.x;
  const int grp = idx >> 8, slot = idx & 255;
  const int bi = (slot & 7) * 32 + (slot >> 3);   // bijective on 256
  const int bh = bi >> 3, base = bi & 7;
  const int qt = grp == 0 ? 15 - base : base;
  const int b = bh >> 4, h = bh & 15;
  const int q0 = qt * 128;

  const u16* Qg = Qb + ((size_t)(b * SEQ + q0) << 10) + h * 64;
  const u16* Kg = Kb + ((size_t)(b * SEQ) << 10) + h * 64;
  const u16* Vg = Vt + ((size_t)(bh * 64) << 11);

  const short8 ones = {0x3F80, 0x3F80, 0x3F80, 0x3F80,
                       0x3F80, 0x3F80, 0x3F80, 0x3F80};   // bf16 1.0 x8

  // prologue: Q (1024 chunks) into Pl[0], K/V tile 0
#pragma unroll
  for (int i = 0; i < 2; ++i) {
    const int c = t + i * 512;
    const int row = c >> 3, col = ((c & 7) ^ (row & 7)) * 8;
    g2l16(Qg + ((size_t)row << 10) + col, Pl + c * 8);
    g2l16(Kg + ((size_t)row << 10) + col, Kl + c * 8);
    const int vr = c >> 4, vc = ((c & 15) ^ (vr & 7)) * 8;
    g2l16(Vg + ((size_t)vr << 11) + vc, Vl + c * 8);
  }
  wait_vm0();
  __syncthreads();

  // Q fragments for both q-halves (both wave-groups read the same rows)
  short8 qf[2][2];
#pragma unroll
  for (int qg = 0; qg < 2; ++qg)
#pragma unroll
    for (int ks = 0; ks < 2; ++ks)
      qf[qg][ks] = *(const short8*)(Pl + (qg * 64 + qrow) * 64 +
                                    ((ks ^ khi) * 4 + gk) * 8);
  __syncthreads();   // qf consumed before gid-0 P writes overwrite Pl[0]

  f32x4 oacc[2][4];
  f32x4 lacc[2] = {f32x4{0.f, 0.f, 0.f, 0.f}, f32x4{0.f, 0.f, 0.f, 0.f}};
#pragma unroll
  for (int qg = 0; qg < 2; ++qg)
#pragma unroll
    for (int dt = 0; dt < 4; ++dt) oacc[qg][dt] = f32x4{0.f, 0.f, 0.f, 0.f};

  u16* Pp = Pl + gid * 8192;
  const int kbase = gid * 64;

  for (int kt = 0; kt <= qt; ++kt) {
    if (kt) {
      __syncthreads();                  // all waves done with previous K/V tile
      const int k0n = kt * 128;
#pragma unroll
      for (int i = 0; i < 2; ++i) {
        const int c = t + i * 512;
        const int row = c >> 3, col = ((c & 7) ^ (row & 7)) * 8;
        g2l16(Kg + ((size_t)(k0n + row) << 10) + col, Kl + c * 8);
        const int vr = c >> 4, vc = ((c & 15) ^ (vr & 7)) * 8;
        g2l16(Vg + ((size_t)vr << 11) + k0n + vc, Vl + c * 8);
      }
      wait_vm0();
      __syncthreads();                  // tile staged (other block's compute covers this drain)
    }
    const bool diag = (kt == qt);
    const bool skip0 = diag && (gid == 1);   // qg0 fully masked for upper keys
    const int k064 = kt * 128 + kbase;

    // S^T: this group's 64 keys x 32 q (kf shared across both q-halves)
    f32x4 sacc[2][4];
#pragma unroll
    for (int qg = 0; qg < 2; ++qg)
#pragma unroll
      for (int mt = 0; mt < 4; ++mt) sacc[qg][mt] = f32x4{0.f, 0.f, 0.f, 0.f};
#pragma unroll
    for (int ks = 0; ks < 2; ++ks)
#pragma unroll
      for (int mt = 0; mt < 4; ++mt) {
        const short8 kf = *(const short8*)(
            Kl + ((kbase + mt * 16 + cl) << 6) + ((ks ^ khi) * 4 + gk) * 8);
        if (!skip0) sacc[0][mt] = mfma16(kf, qf[0][ks], sacc[0][mt]);
        sacc[1][mt] = mfma16(kf, qf[1][ks], sacc[1][mt]);
      }
    // softmax (exp2 domain), P into swizzled wave-private rows of Pp
#pragma unroll
    for (int qg = 0; qg < 2; ++qg) {
      if (qg == 0 && skip0) continue;
      const bool maskit = diag && ((qg == 0) ? (gid == 0) : (gid == 1));
      const int qglob = q0 + qg * 64 + qrow;
#pragma unroll
      for (int mt = 0; mt < 4; ++mt) {
        const int keyg = k064 + mt * 16 + g * 4;
        float p0 = fexp2(sacc[qg][mt][0]);
        float p1 = fexp2(sacc[qg][mt][1]);
        float p2 = fexp2(sacc[qg][mt][2]);
        float p3 = fexp2(sacc[qg][mt][3]);
        if (maskit) {
          if (keyg + 0 > qglob) p0 = 0.f;
          if (keyg + 1 > qglob) p1 = 0.f;
          if (keyg + 2 > qglob) p2 = 0.f;
          if (keyg + 3 > qglob) p3 = 0.f;
        }
        uint2 pk;
        pk.x = pkbf(p0, p1);
        pk.y = pkbf(p2, p3);
        const int pchunk = (mt * 2 + (g >> 1)) ^ (cl & 7);
        *(uint2*)(Pp + (qg * 64 + qrow) * 64 + pchunk * 8 + (g & 1) * 4) = pk;
      }
    }
    // O^T += V^T * P^T ; l += ones * P^T  (vf shared across q-halves)
#pragma unroll
    for (int ks = 0; ks < 2; ++ks) {
      short8 pf0, pf1;
      if (!skip0)
        pf0 = *(const short8*)(Pp + qrow * 64 + ((ks ^ khi) * 4 + gk) * 8);
      pf1 = *(const short8*)(Pp + (64 + qrow) * 64 + ((ks ^ khi) * 4 + gk) * 8);
      if (!skip0) lacc[0] = mfma16(ones, pf0, lacc[0]);
      lacc[1] = mfma16(ones, pf1, lacc[1]);
#pragma unroll
      for (int dt = 0; dt < 4; ++dt) {
        const short8 vf = *(const short8*)(
            Vl + ((dt * 16 + cl) << 7) + (kbase / 8 + (ks ^ khi) * 4 + gk) * 8);
        if (!skip0) oacc[0][dt] = mfma16(vf, pf0, oacc[0][dt]);
        oacc[1][dt] = mfma16(vf, pf1, oacc[1][dt]);
      }
    }
  }

  // ---- in-block combine (linear: O = O_A + O_B, l = l_A + l_B) ----
  __syncthreads();                      // all waves done reading K/V/P
  if (gid == 1) {
#pragma unroll
    for (int qg = 0; qg < 2; ++qg) {
#pragma unroll
      for (int dt = 0; dt < 4; ++dt)
        *(f32x4*)(Oc + (qg * 64 + qrow) * 68 + dt * 16 + g * 4) = oacc[qg][dt];
      if (g == 0) Lc[qg * 64 + qrow] = lacc[qg][0];
    }
  }
  __syncthreads();
  if (gid == 0) {
#pragma unroll
    for (int qg = 0; qg < 2; ++qg) {
      const float l = lacc[qg][0] + Lc[qg * 64 + qrow];
      const float inv = 1.f / l;
      const size_t qgl = (size_t)(b * SEQ + q0 + qg * 64 + qrow);
#pragma unroll
      for (int dt = 0; dt < 4; ++dt) {
        const f32x4 ov =
            *(const f32x4*)(Oc + (qg * 64 + qrow) * 68 + dt * 16 + g * 4);
        uint2 o;
        o.x = pkbf((oacc[qg][dt][0] + ov[0]) * inv,
                   (oacc[qg][dt][1] + ov[1]) * inv);
        o.y = pkbf((oacc[qg][dt][2] + ov[2]) * inv,
                   (oacc[qg][dt][3] + ov[3]) * inv);
        *(uint2*)(Ob + (qgl << 10) + h * 64 + dt * 16 + g * 4) = o;
      }
    }
  }
}

// ---------------- output projection: fp32 out = Ob * wo^T, 128x128 tiles -----
// 256 blocks (32m x 8n) = exactly 1/CU; gemm_core_db<4> (R1-verified core):
// per-wave 64x64, compute:LDS-read ratio 2.0 (vs 1.33 at NB=2).
__global__ __launch_bounds__(256) void gemm_out(const u16* __restrict__ Ab,
                                                const u16* __restrict__ Wb,
                                                float* __restrict__ out) {
  __shared__ u16 Al[2 * 128 * 32];
  __shared__ u16 Bl[2 * 128 * 32];
  const int t = threadIdx.x, L = t & 63, w = t >> 6;
  const int wm = (w >> 1) * 64, wn = (w & 1) * 64;
  const int bx = blockIdx.x;
  const int m0 = (bx & 31) * 128;
  const int n0 = (bx >> 5) * 128;

  f32x4 acc[4][4];
#pragma unroll
  for (int i = 0; i < 4; ++i)
#pragma unroll
    for (int j = 0; j < 4; ++j) acc[i][j] = f32x4{0.f, 0.f, 0.f, 0.f};

  gemm_core_db<4>(Ab, Wb, m0, n0, Al, Bl, acc, t);

  const int rl = (L >> 4) * 4, cl = L & 15;
#pragma unroll
  for (int mt = 0; mt < 4; ++mt)
#pragma unroll
    for (int nt = 0; nt < 4; ++nt) {
      const int n = n0 + wn + nt * 16 + cl;
#pragma unroll
      for (int r = 0; r < 4; ++r) {
        const int m = m0 + wm + mt * 16 + rl + r;
        out[(size_t)m * EMB + n] = acc[mt][nt][r];
      }
    }
}

// ---------------- launch ----------------
extern "C" void kernel_launch(void* const* d_in, const int* in_sizes, int n_in,
                              void* d_out, int out_size, void* d_ws, size_t ws_size,
                              hipStream_t stream) {
  const float* x  = (const float*)d_in[0];
  const float* wq = (const float*)d_in[1];
  const float* wk = (const float*)d_in[2];
  const float* wv = (const float*)d_in[3];
  const float* wo = (const float*)d_in[4];
  float* out = (float*)d_out;

  char* ws = (char*)d_ws;
  u16* xb  = (u16*)(ws);                          // 8 MB  [4096][1024]
  u16* wqb = (u16*)(ws + ((size_t)8  << 20));     // 2 MB
  u16* wkb = (u16*)(ws + ((size_t)10 << 20));     // 2 MB
  u16* wvb = (u16*)(ws + ((size_t)12 << 20));     // 2 MB
  u16* wob = (u16*)(ws + ((size_t)14 << 20));     // 2 MB
  u16* Qb  = (u16*)(ws + ((size_t)16 << 20));     // 8 MB  pre-scaled by 0.125*log2e
  u16* Kb  = (u16*)(ws + ((size_t)24 << 20));     // 8 MB
  u16* Vt  = (u16*)(ws + ((size_t)32 << 20));     // 8 MB  [32*64][2048] transposed
  u16* Ob  = (u16*)(ws + ((size_t)40 << 20));     // 8 MB

  cvt_all<<<8192, 256, 0, stream>>>(x, wq, wk, wv, wo, xb, wqb, wkb, wvb, wob);
  gemm_qkv<<<192, 512, 0, stream>>>(xb, wqb, wkb, wvb, Qb, Kb, Vt);
  attn<<<512, 512, 0, stream>>>(Qb, Kb, Vt, Ob);
  gemm_out<<<256, 256, 0, stream>>>(Ob, wob, out);
}

// Round 9
// 171.820 us; speedup vs baseline: 1.1136x; 1.1136x over previous
//
#include <hip/hip_runtime.h>
#include <stdint.h>

#define DI __device__ __forceinline__

typedef __attribute__((ext_vector_type(8))) short short8;
typedef __attribute__((ext_vector_type(8))) __bf16 bf16x8;
typedef __attribute__((ext_vector_type(2))) __bf16 bf16x2;
typedef __attribute__((ext_vector_type(4))) float f32x4;
typedef unsigned short u16;

static constexpr int SEQ = 2048;
static constexpr int EMB = 1024;

// round-to-nearest-even fp32 -> bf16
DI u16 f2bf(float x) {
  uint32_t u = __float_as_uint(x);
  u += 0x7fffu + ((u >> 16) & 1u);
  return (u16)(u >> 16);
}

DI uint32_t pkbf(float a, float b) {
#if __has_builtin(__builtin_amdgcn_cvt_pk_bf16_f32)
  bf16x2 v = __builtin_amdgcn_cvt_pk_bf16_f32(a, b);
  return __builtin_bit_cast(uint32_t, v);
#else
  return (uint32_t)f2bf(a) | ((uint32_t)f2bf(b) << 16);
#endif
}

DI float fexp2(float x) {
#if __has_builtin(__builtin_amdgcn_exp2f)
  return __builtin_amdgcn_exp2f(x);
#else
  return exp2f(x);
#endif
}

DI f32x4 mfma16(short8 a, short8 b, f32x4 c) {
  return __builtin_amdgcn_mfma_f32_16x16x32_bf16(
      __builtin_bit_cast(bf16x8, a), __builtin_bit_cast(bf16x8, b), c, 0, 0, 0);
}

// async global->LDS, 16B per lane; LDS dest = wave-uniform base + lane*16
DI void g2l16(const u16* g, u16* l) {
  __builtin_amdgcn_global_load_lds(
      (const __attribute__((address_space(1))) unsigned int*)g,
      (__attribute__((address_space(3))) unsigned int*)l, 16, 0, 0);
}

// s_waitcnt imms: vm bits[3:0]+[15:14], exp [6:4], lgkm [11:8]
DI void wait_vm0() { __builtin_amdgcn_s_waitcnt(0x0F70); }   // vmcnt(0) only
DI void wait_vm4() { __builtin_amdgcn_s_waitcnt(0x0F74); }   // vmcnt(4) only
DI void wait_vm6() { __builtin_amdgcn_s_waitcnt(0x0F76); }   // vmcnt(6) only
DI void wait_lgkm0() { __builtin_amdgcn_s_waitcnt(0xC07F); } // lgkmcnt(0) only
DI void memfence_c() { asm volatile("" ::: "memory"); }      // compiler-only fence

// ---------------- fused fp32 -> bf16 conversion (all 5 tensors) ----------------
__global__ __launch_bounds__(256) void cvt_all(
    const float* __restrict__ x,  const float* __restrict__ wq,
    const float* __restrict__ wk, const float* __restrict__ wv,
    const float* __restrict__ wo,
    u16* __restrict__ xb, u16* __restrict__ wqb, u16* __restrict__ wkb,
    u16* __restrict__ wvb, u16* __restrict__ wob) {
  const int bx = blockIdx.x;
  const float* s; u16* d; int off;
  if (bx < 4096) { s = x; d = xb; off = bx << 8; }
  else {
    const int r = bx - 4096, wsel = r >> 10;
    off = (r & 1023) << 8;
    s = wsel == 0 ? wq : (wsel == 1 ? wk : (wsel == 2 ? wv : wo));
    d = wsel == 0 ? wqb : (wsel == 1 ? wkb : (wsel == 2 ? wvb : wob));
  }
  const int i = off + threadIdx.x;
  float4 v = ((const float4*)s)[i];
  uint2 o;
  o.x = pkbf(v.x, v.y);
  o.y = pkbf(v.z, v.w);
  ((uint2*)d)[i] = o;
}

// ------- double-buffered GEMM K-loop, BK=32 (used by gemm_out) --------------
template <int NB>   // b-subtiles per wave: 4 -> BN=128, 2 -> BN=64
DI void gemm_core_db(const u16* __restrict__ A, const u16* __restrict__ B,
                     int m0, int n0, u16* Al, u16* Bl, f32x4 (&acc)[4][NB],
                     int t) {
  const int L = t & 63, w = t >> 6;
  const int wm = (w >> 1) * 64, wn = (w & 1) * (NB * 16);
  const int r = L & 15, g = L >> 4;
  const int gofs = (g ^ ((L >> 1) & 3)) * 8;
  const int scol = (((t & 3) ^ ((t >> 3) & 3)) * 8);
  const int arow0 = t >> 2, arow1 = (t + 256) >> 2;
  const u16* Ap0 = A + ((size_t)(m0 + arow0) << 10) + scol;
  const u16* Ap1 = A + ((size_t)(m0 + arow1) << 10) + scol;
  const u16* Bp0 = B + ((size_t)(n0 + arow0) << 10) + scol;
  const u16* Bp1 = B + ((size_t)(n0 + arow1) << 10) + scol;
  constexpr int AH = 128 * 32;      // elems per A half
  constexpr int BH = NB * 32 * 32;  // elems per B half

  // prologue: stage tile 0 into half 0
  g2l16(Ap0, Al + t * 8);
  g2l16(Ap1, Al + (t + 256) * 8);
  g2l16(Bp0, Bl + t * 8);
  if (NB == 4) g2l16(Bp1, Bl + (t + 256) * 8);
  wait_vm0();
  __syncthreads();

  for (int ks = 0; ks < 32; ++ks) {
    const int cur = ks & 1;
    const u16* Alc = Al + cur * AH;
    const u16* Blc = Bl + cur * BH;
    if (ks < 31) {                        // prefetch tile ks+1 (async, no wait)
      const int k0 = (ks + 1) * 32;
      u16* Aln = Al + (cur ^ 1) * AH;
      u16* Bln = Bl + (cur ^ 1) * BH;
      g2l16(Ap0 + k0, Aln + t * 8);
      g2l16(Ap1 + k0, Aln + (t + 256) * 8);
      g2l16(Bp0 + k0, Bln + t * 8);
      if (NB == 4) g2l16(Bp1 + k0, Bln + (t + 256) * 8);
    }
    short8 af[4], bfr[NB];
#pragma unroll
    for (int mt = 0; mt < 4; ++mt)
      af[mt] = *(const short8*)(Alc + (wm + mt * 16 + r) * 32 + gofs);
#pragma unroll
    for (int nt = 0; nt < NB; ++nt)
      bfr[nt] = *(const short8*)(Blc + (wn + nt * 16 + r) * 32 + gofs);
#pragma unroll
    for (int mt = 0; mt < 4; ++mt)
#pragma unroll
      for (int nt = 0; nt < NB; ++nt)
        acc[mt][nt] = mfma16(af[mt], bfr[nt], acc[mt][nt]);
    if (ks < 31) {
      wait_vm0();                         // prefetch landed (after compute!)
      __syncthreads();                    // one barrier per iter
    }
  }
}

// ---------------- fused QKV projection: 8-phase 256x256 schedule -------------
// (verified round 5) C[4096 x 3072] = xb * W^T, K=1024. 192 blocks, 512 thr
// (8 waves = 2M x 4N), per-wave 128x64. BK=64. LDS 128 KB, XOR-8 swizzle.
// Counted vmcnt(6): 3 half-tiles stay in flight across raw s_barriers.
__global__ __launch_bounds__(512, 2) void gemm_qkv(
    const u16* __restrict__ xb,
    const u16* __restrict__ wqb, const u16* __restrict__ wkb,
    const u16* __restrict__ wvb,
    u16* __restrict__ Qb, u16* __restrict__ Kb, u16* __restrict__ Vt) {
  __shared__ u16 Al[2 * 256 * 64];      // 64 KB
  __shared__ u16 Bl[2 * 256 * 64];      // 64 KB
  const int t = threadIdx.x, L = t & 63, w = t >> 6;
  const int wm = (w >> 2) * 128, wn = (w & 3) * 64;
  const int r = L & 15, g = L >> 4;
  const int e = r & 7;
  const int ck0 = (g ^ e) * 8, ck1 = ((4 + g) ^ e) * 8;   // chunk for ks=0/1
  const int arow = wm >> 1;    // within-half j offset for A frag reads
  const int brow = wn >> 1;    // within-half j offset for B frag reads

  const int bx = blockIdx.x;
  const int m0 = (bx & 15) * 256;
  const int n0 = (bx >> 4) * 256;
  const int which = n0 >> 10;                 // 0:Q 1:K 2:V
  const u16* wsel = which == 0 ? wqb : (which == 1 ? wkb : wvb);
  const int nl0 = n0 & 1023;

  // staging constants: thread handles half-chunks c0=t (j 0..63), c1=t+512
  const int j0 = t >> 3, j1 = (t + 512) >> 3;
  const int sc0 = ((t & 7) ^ (j0 & 7)) * 8;
  const int sc1 = (((t + 512) & 7) ^ (j1 & 7)) * 8;
  const int ar0 = (j0 >> 6) * 128 + (j0 & 63);   // A half-0 row (h adds 64)
  const int ar1 = (j1 >> 6) * 128 + (j1 & 63);
  const int br0 = (j0 >> 5) * 64 + (j0 & 31);    // B half-0 row (h adds 32)
  const int br1 = (j1 >> 5) * 64 + (j1 & 31);
  const u16* As0 = xb + ((size_t)(m0 + ar0) << 10) + sc0;
  const u16* As1 = xb + ((size_t)(m0 + ar1) << 10) + sc1;
  const u16* Bs0 = wsel + ((size_t)(nl0 + br0) << 10) + sc0;
  const u16* Bs1 = wsel + ((size_t)(nl0 + br1) << 10) + sc1;

  f32x4 acc[8][4];
#pragma unroll
  for (int i = 0; i < 8; ++i)
#pragma unroll
    for (int j = 0; j < 4; ++j) acc[i][j] = f32x4{0.f, 0.f, 0.f, 0.f};
  short8 af[4][2], bn[4][2];

#define STG_A(kt, h)                                                          \
  { const size_t ko = (size_t)(kt) * 64 + (size_t)(h) * (64 << 10);           \
    u16* dd = Al + (((kt) & 1) << 14) + ((h) << 13);                          \
    g2l16(As0 + ko, dd + t * 8);                                              \
    g2l16(As1 + ko, dd + (t + 512) * 8); }
#define STG_B(kt, h)                                                          \
  { const size_t ko = (size_t)(kt) * 64 + (size_t)(h) * (32 << 10);           \
    u16* dd = Bl + (((kt) & 1) << 14) + ((h) << 13);                          \
    g2l16(Bs0 + ko, dd + t * 8);                                              \
    g2l16(Bs1 + ko, dd + (t + 512) * 8); }
#define LDA(bs, mh)                                                           \
  _Pragma("unroll") for (int mf = 0; mf < 4; ++mf) {                          \
    const u16* p = Al + ((bs) << 14) + ((mh) << 13) +                         \
                   (arow + mf * 16 + r) * 64;                                 \
    af[mf][0] = *(const short8*)(p + ck0);                                    \
    af[mf][1] = *(const short8*)(p + ck1); }
#define LDB(bs, nh)                                                           \
  _Pragma("unroll") for (int nf = 0; nf < 2; ++nf) {                          \
    const u16* p = Bl + ((bs) << 14) + ((nh) << 13) +                         \
                   (brow + nf * 16 + r) * 64;                                 \
    bn[(nh) * 2 + nf][0] = *(const short8*)(p + ck0);                         \
    bn[(nh) * 2 + nf][1] = *(const short8*)(p + ck1); }
#define MM(mh, nh)                                                            \
  _Pragma("unroll") for (int ks = 0; ks < 2; ++ks)                            \
  _Pragma("unroll") for (int mf = 0; mf < 4; ++mf)                            \
  _Pragma("unroll") for (int nf = 0; nf < 2; ++nf)                            \
    acc[(mh) * 4 + mf][(nh) * 2 + nf] = mfma16(                               \
        af[mf][ks], bn[(nh) * 2 + nf][ks], acc[(mh) * 4 + mf][(nh) * 2 + nf]);
#define PH_MID()                                                              \
  { memfence_c(); __builtin_amdgcn_s_barrier(); memfence_c();                 \
    wait_lgkm0(); __builtin_amdgcn_sched_barrier(0);                          \
    __builtin_amdgcn_s_setprio(1); }
#define PH_END()                                                              \
  { __builtin_amdgcn_s_setprio(0); __builtin_amdgcn_sched_barrier(0);         \
    memfence_c(); __builtin_amdgcn_s_barrier(); memfence_c(); }
// VMODE: 0 -> vmcnt(6), 1 -> vmcnt(0), 2 -> none
#define TILE(tt, S1, S2, VMODE)                                               \
  { const int bs_ = (tt) & 1;                                                 \
    LDA(bs_, 0); LDB(bs_, 0);                                                 \
    if (S1) STG_A((tt) + 1, 1);                                               \
    PH_MID(); MM(0, 0); PH_END();                                             \
    LDB(bs_, 1);                                                              \
    if (S2) STG_A((tt) + 2, 0);                                               \
    PH_MID(); MM(0, 1); PH_END();                                             \
    LDA(bs_, 1);                                                              \
    if (S2) STG_B((tt) + 2, 0);                                               \
    PH_MID(); MM(1, 1); PH_END();                                             \
    if (S2) STG_B((tt) + 2, 1);                                               \
    if ((VMODE) == 0) wait_vm6();                                             \
    else if ((VMODE) == 1) wait_vm0();                                        \
    PH_MID(); MM(1, 0); PH_END(); }

  // prologue: tiles 0 (all 4 halves) + tile 1 (3 halves); vmcnt(6) -> tile 0
  // fully landed (newest 3 halves may still be in flight)
  STG_A(0, 0); STG_B(0, 0); STG_B(0, 1); STG_A(0, 1);
  STG_A(1, 0); STG_B(1, 0); STG_B(1, 1);
  wait_vm6();
  memfence_c(); __builtin_amdgcn_s_barrier(); memfence_c();

  for (int tp = 0; tp < 7; ++tp) {      // tiles 0..13, buffer parity folded
    TILE(2 * tp, 1, 1, 0);
    TILE(2 * tp + 1, 1, 1, 0);
  }
  TILE(14, 1, 0, 1);                    // stage A-h1(15) only; drain vmcnt(0)
  TILE(15, 0, 0, 2);                    // no stages, no vmcnt

#undef STG_A
#undef STG_B
#undef LDA
#undef LDB
#undef MM
#undef PH_MID
#undef PH_END
#undef TILE

  // epilogue
  const int rl = (L >> 4) * 4, cl = L & 15;
  if (which < 2) {
    u16* outp = which == 0 ? Qb : Kb;
    // fold 1/sqrt(64) * log2(e) into Q (softmax runs in exp2 domain)
    const float sc = which == 0 ? 0.125f * 1.44269504089f : 1.0f;
#pragma unroll
    for (int mt = 0; mt < 8; ++mt) {
#pragma unroll
      for (int nt = 0; nt < 4; ++nt) {
        const int n = nl0 + wn + nt * 16 + cl;
#pragma unroll
        for (int rr = 0; rr < 4; ++rr) {
          const int m = m0 + wm + mt * 16 + rl + rr;
          outp[(size_t)m * EMB + n] = f2bf(acc[mt][nt][rr] * sc);
        }
      }
    }
  } else {
    // V: write transposed per head: Vt[(b*16+h)*64 + d][s]
#pragma unroll
    for (int mt = 0; mt < 8; ++mt) {
      const int mbase = m0 + wm + mt * 16 + rl;
      const int b = mbase >> 11, s = mbase & 2047;
#pragma unroll
      for (int nt = 0; nt < 4; ++nt) {
        const int n = nl0 + wn + nt * 16 + cl;
        const int h = n >> 6, d = n & 63;
        uint2 o;
        o.x = pkbf(acc[mt][nt][0], acc[mt][nt][1]);
        o.y = pkbf(acc[mt][nt][2], acc[mt][nt][3]);
        *(uint2*)(Vt + ((size_t)((b * 16 + h) * 64 + d) << 11) + s) = o;
      }
    }
  }
}

// ---------- flash attention (causal), in-block key-split, P in LDS ----------
// v9 = R4/R5-verified attn (2 jobs/block {15-base, base} = 17 tiles, 8 waves,
// wave-group key-split, ones-MFMA l, in-block linear combine) with the K/V
// pipeline deepened: TRIPLE-buffered K/V + counted vmcnt(4) (T4 pattern,
// verified in gemm_qkv). Invariant: at end of iter j, outstanding = exactly
// stage(j+2)'s 4 loads -> stage(j+1) has landed; write-after-read protected
// by the per-iter barrier (stage(j+2) targets the buffer last read two
// barriers back, in compute(j-1)). LDS 48K(K) + 48K(V) + 32K(P) = 128 KB.
__global__ __launch_bounds__(512, 1) void attn(
    const u16* __restrict__ Qb, const u16* __restrict__ Kb,
    const u16* __restrict__ Vt, u16* __restrict__ Ob) {
  __shared__ __align__(16) u16 smem[65536];   // 128 KB
  u16* Kl = smem;                             // [3][128 key][64 d]  XOR-8 (48K)
  u16* Vl = smem + 24576;                     // [3][64 d][128 key]  XOR-8 (48K)
  u16* Pl = smem + 49152;                     // [2 gid][128 q][64 key] (32K); Q in Pl[0]
  float* Oc = (float*)smem;                   // combine: [128][68] f32 (34816 B, dead K region)
  float* Lc = (float*)(smem + 17408);         // 128 f32 @ byte 34816 (dead K region)

  const int t = threadIdx.x, w = t >> 6, gid = w >> 2, wl = w & 3;
  const int L = t & 63, g = L >> 4, cl = L & 15;
  const int gk = g ^ (cl & 3);          // swizzled low chunk bits for frag reads
  const int khi = (cl >> 2) & 1;        // swizzled high chunk bit
  const int qrow = wl * 16 + cl;

  // XCD-contiguous reindex: 4 heads per XCD -> K/V (2 MB) hot in 4 MB L2
  const int bi = (blockIdx.x & 7) * 32 + (blockIdx.x >> 3);   // bijective, 256
  const int bh = bi >> 3, base = bi & 7;
  const int b = bh >> 4, h = bh & 15;

  const u16* Kg = Kb + ((size_t)(b * SEQ) << 10) + h * 64;
  const u16* Vg = Vt + ((size_t)(bh * 64) << 11);

  const short8 ones = {0x3F80, 0x3F80, 0x3F80, 0x3F80,
                       0x3F80, 0x3F80, 0x3F80, 0x3F80};   // bf16 1.0 x8

  for (int job = 0; job < 2; ++job) {
    const int qt = job == 0 ? 15 - base : base;
    const int q0 = qt * 128;
    const u16* Qg = Qb + ((size_t)(b * SEQ + q0) << 10) + h * 64;

    // prologue: Q (1024 chunks) into Pl[0]; stage tile 0 (buf 0) and, if
    // present, tile 1 (buf 1). Per-thread loads: Q=2, per tile K2+V2=4.
#pragma unroll
    for (int i = 0; i < 2; ++i) {
      const int c = t + i * 512;
      const int row = c >> 3, col = ((c & 7) ^ (row & 7)) * 8;
      g2l16(Qg + ((size_t)row << 10) + col, Pl + c * 8);
    }
#pragma unroll
    for (int i = 0; i < 2; ++i) {
      const int c = t + i * 512;
      const int row = c >> 3, col = ((c & 7) ^ (row & 7)) * 8;
      g2l16(Kg + ((size_t)row << 10) + col, Kl + c * 8);
      const int vr = c >> 4, vc = ((c & 15) ^ (vr & 7)) * 8;
      g2l16(Vg + ((size_t)vr << 11) + vc, Vl + c * 8);
    }
    if (qt >= 1) {
#pragma unroll
      for (int i = 0; i < 2; ++i) {
        const int c = t + i * 512;
        const int row = c >> 3, col = ((c & 7) ^ (row & 7)) * 8;
        g2l16(Kg + ((size_t)(128 + row) << 10) + col, Kl + 8192 + c * 8);
        const int vr = c >> 4, vc = ((c & 15) ^ (vr & 7)) * 8;
        g2l16(Vg + ((size_t)vr << 11) + 128 + vc, Vl + 8192 + c * 8);
      }
      wait_vm4();                       // Q + tile 0 landed; tile 1 in flight
    } else {
      wait_vm0();
    }
    __syncthreads();

    // Q fragments for both q-halves (both wave-groups read the same rows)
    short8 qf[2][2];
#pragma unroll
    for (int qg = 0; qg < 2; ++qg)
#pragma unroll
      for (int ks = 0; ks < 2; ++ks)
        qf[qg][ks] = *(const short8*)(Pl + (qg * 64 + qrow) * 64 +
                                      ((ks ^ khi) * 4 + gk) * 8);
    __syncthreads();   // qf consumed before gid-0 P writes overwrite Pl[0]

    f32x4 oacc[2][4];
    f32x4 lacc[2] = {f32x4{0.f, 0.f, 0.f, 0.f}, f32x4{0.f, 0.f, 0.f, 0.f}};
#pragma unroll
    for (int qg = 0; qg < 2; ++qg)
#pragma unroll
      for (int dt = 0; dt < 4; ++dt) oacc[qg][dt] = f32x4{0.f, 0.f, 0.f, 0.f};

    u16* Pp = Pl + gid * 8192;
    const int kbase = gid * 64;

    for (int kt = 0; kt <= qt; ++kt) {
      const int cur = kt % 3;
      const u16* Klc = Kl + cur * 8192;
      const u16* Vlc = Vl + cur * 8192;
      if (kt + 2 <= qt) {                 // prefetch tile kt+2 (async, no wait)
        const int b2 = (kt + 2) % 3;
        const int k0n = (kt + 2) * 128;
        u16* Kln = Kl + b2 * 8192;
        u16* Vln = Vl + b2 * 8192;
#pragma unroll
        for (int i = 0; i < 2; ++i) {
          const int c = t + i * 512;
          const int row = c >> 3, col = ((c & 7) ^ (row & 7)) * 8;
          g2l16(Kg + ((size_t)(k0n + row) << 10) + col, Kln + c * 8);
          const int vr = c >> 4, vc = ((c & 15) ^ (vr & 7)) * 8;
          g2l16(Vg + ((size_t)vr << 11) + k0n + vc, Vln + c * 8);
        }
      }
      const bool diag = (kt == qt);
      const bool skip0 = diag && (gid == 1);   // qg0 fully masked for upper keys
      const int k064 = kt * 128 + kbase;

      // S^T: this group's 64 keys x 32 q (kf shared across both q-halves)
      f32x4 sacc[2][4];
#pragma unroll
      for (int qg = 0; qg < 2; ++qg)
#pragma unroll
        for (int mt = 0; mt < 4; ++mt) sacc[qg][mt] = f32x4{0.f, 0.f, 0.f, 0.f};
#pragma unroll
      for (int ks = 0; ks < 2; ++ks)
#pragma unroll
        for (int mt = 0; mt < 4; ++mt) {
          const short8 kf = *(const short8*)(
              Klc + ((kbase + mt * 16 + cl) << 6) + ((ks ^ khi) * 4 + gk) * 8);
          if (!skip0) sacc[0][mt] = mfma16(kf, qf[0][ks], sacc[0][mt]);
          sacc[1][mt] = mfma16(kf, qf[1][ks], sacc[1][mt]);
        }
      // softmax (exp2 domain), P into swizzled wave-private rows of Pp
#pragma unroll
      for (int qg = 0; qg < 2; ++qg) {
        if (qg == 0 && skip0) continue;
        const bool maskit = diag && ((qg == 0) ? (gid == 0) : (gid == 1));
        const int qglob = q0 + qg * 64 + qrow;
#pragma unroll
        for (int mt = 0; mt < 4; ++mt) {
          const int keyg = k064 + mt * 16 + g * 4;
          float p0 = fexp2(sacc[qg][mt][0]);
          float p1 = fexp2(sacc[qg][mt][1]);
          float p2 = fexp2(sacc[qg][mt][2]);
          float p3 = fexp2(sacc[qg][mt][3]);
          if (maskit) {
            if (keyg + 0 > qglob) p0 = 0.f;
            if (keyg + 1 > qglob) p1 = 0.f;
            if (keyg + 2 > qglob) p2 = 0.f;
            if (keyg + 3 > qglob) p3 = 0.f;
          }
          uint2 pk;
          pk.x = pkbf(p0, p1);
          pk.y = pkbf(p2, p3);
          const int pchunk = (mt * 2 + (g >> 1)) ^ (cl & 7);
          *(uint2*)(Pp + (qg * 64 + qrow) * 64 + pchunk * 8 + (g & 1) * 4) = pk;
        }
      }
      // O^T += V^T * P^T ; l += ones * P^T  (vf shared across q-halves)
#pragma unroll
      for (int ks = 0; ks < 2; ++ks) {
        short8 pf0, pf1;
        if (!skip0)
          pf0 = *(const short8*)(Pp + qrow * 64 + ((ks ^ khi) * 4 + gk) * 8);
        pf1 = *(const short8*)(Pp + (64 + qrow) * 64 + ((ks ^ khi) * 4 + gk) * 8);
        if (!skip0) lacc[0] = mfma16(ones, pf0, lacc[0]);
        lacc[1] = mfma16(ones, pf1, lacc[1]);
#pragma unroll
        for (int dt = 0; dt < 4; ++dt) {
          const short8 vf = *(const short8*)(
              Vlc + ((dt * 16 + cl) << 7) + (kbase / 8 + (ks ^ khi) * 4 + gk) * 8);
          if (!skip0) oacc[0][dt] = mfma16(vf, pf0, oacc[0][dt]);
          oacc[1][dt] = mfma16(vf, pf1, oacc[1][dt]);
        }
      }
      if (kt < qt) {
        if (kt + 2 <= qt) wait_vm4();     // tile kt+1 landed; kt+2 in flight
        else wait_vm0();                  // tail: drain everything
        __syncthreads();                  // one barrier per 128-key tile
      }
    }

    // ---- in-block combine (linear: O = O_A + O_B, l = l_A + l_B) ----
    __syncthreads();                      // all waves done reading K/V/P
    if (gid == 1) {
#pragma unroll
      for (int qg = 0; qg < 2; ++qg) {
#pragma unroll
        for (int dt = 0; dt < 4; ++dt)
          *(f32x4*)(Oc + (qg * 64 + qrow) * 68 + dt * 16 + g * 4) = oacc[qg][dt];
        if (g == 0) Lc[qg * 64 + qrow] = lacc[qg][0];
      }
    }
    __syncthreads();
    if (gid == 0) {
#pragma unroll
      for (int qg = 0; qg < 2; ++qg) {
        const float l = lacc[qg][0] + Lc[qg * 64 + qrow];
        const float inv = 1.f / l;
        const size_t qgl = (size_t)(b * SEQ + q0 + qg * 64 + qrow);
#pragma unroll
        for (int dt = 0; dt < 4; ++dt) {
          const f32x4 ov =
              *(const f32x4*)(Oc + (qg * 64 + qrow) * 68 + dt * 16 + g * 4);
          uint2 o;
          o.x = pkbf((oacc[qg][dt][0] + ov[0]) * inv,
                     (oacc[qg][dt][1] + ov[1]) * inv);
          o.y = pkbf((oacc[qg][dt][2] + ov[2]) * inv,
                     (oacc[qg][dt][3] + ov[3]) * inv);
          *(uint2*)(Ob + (qgl << 10) + h * 64 + dt * 16 + g * 4) = o;
        }
      }
    }
    __syncthreads();                      // combine reads done before next job's staging
  }
}

// ---------------- output projection: fp32 out = Ob * wo^T, 128x64 tiles ------
__global__ __launch_bounds__(256) void gemm_out(const u16* __restrict__ Ab,
                                                const u16* __restrict__ Wb,
                                                float* __restrict__ out) {
  __shared__ u16 Al[2 * 128 * 32];
  __shared__ u16 Bl[2 * 64 * 32];
  const int t = threadIdx.x, L = t & 63, w = t >> 6;
  const int wm = (w >> 1) * 64, wn = (w & 1) * 32;
  const int bx = blockIdx.x;
  const int m0 = (bx & 31) * 128;
  const int n0 = (bx >> 5) * 64;

  f32x4 acc[4][2];
#pragma unroll
  for (int i = 0; i < 4; ++i)
#pragma unroll
    for (int j = 0; j < 2; ++j) acc[i][j] = f32x4{0.f, 0.f, 0.f, 0.f};

  gemm_core_db<2>(Ab, Wb, m0, n0, Al, Bl, acc, t);

  const int rl = (L >> 4) * 4, cl = L & 15;
#pragma unroll
  for (int mt = 0; mt < 4; ++mt)
#pragma unroll
    for (int nt = 0; nt < 2; ++nt) {
      const int n = n0 + wn + nt * 16 + cl;
#pragma unroll
      for (int r = 0; r < 4; ++r) {
        const int m = m0 + wm + mt * 16 + rl + r;
        out[(size_t)m * EMB + n] = acc[mt][nt][r];
      }
    }
}

// ---------------- launch ----------------
extern "C" void kernel_launch(void* const* d_in, const int* in_sizes, int n_in,
                              void* d_out, int out_size, void* d_ws, size_t ws_size,
                              hipStream_t stream) {
  const float* x  = (const float*)d_in[0];
  const float* wq = (const float*)d_in[1];
  const float* wk = (const float*)d_in[2];
  const float* wv = (const float*)d_in[3];
  const float* wo = (const float*)d_in[4];
  float* out = (float*)d_out;

  char* ws = (char*)d_ws;
  u16* xb  = (u16*)(ws);                          // 8 MB  [4096][1024]
  u16* wqb = (u16*)(ws + ((size_t)8  << 20));     // 2 MB
  u16* wkb = (u16*)(ws + ((size_t)10 << 20));     // 2 MB
  u16* wvb = (u16*)(ws + ((size_t)12 << 20));     // 2 MB
  u16* wob = (u16*)(ws + ((size_t)14 << 20));     // 2 MB
  u16* Qb  = (u16*)(ws + ((size_t)16 << 20));     // 8 MB  pre-scaled by 0.125*log2e
  u16* Kb  = (u16*)(ws + ((size_t)24 << 20));     // 8 MB
  u16* Vt  = (u16*)(ws + ((size_t)32 << 20));     // 8 MB  [32*64][2048] transposed
  u16* Ob  = (u16*)(ws + ((size_t)40 << 20));     // 8 MB

  cvt_all<<<8192, 256, 0, stream>>>(x, wq, wk, wv, wo, xb, wqb, wkb, wvb, wob);
  gemm_qkv<<<192, 512, 0, stream>>>(xb, wqb, wkb, wvb, Qb, Kb, Vt);
  attn<<<256, 512, 0, stream>>>(Qb, Kb, Vt, Ob);
  gemm_out<<<512, 256, 0, stream>>>(Ob, wob, out);
}

// Round 10
// 166.312 us; speedup vs baseline: 1.1505x; 1.0331x over previous
//
#include <hip/hip_runtime.h>
#include <stdint.h>

#define DI __device__ __forceinline__

typedef __attribute__((ext_vector_type(8))) short short8;
typedef __attribute__((ext_vector_type(8))) __bf16 bf16x8;
typedef __attribute__((ext_vector_type(2))) __bf16 bf16x2;
typedef __attribute__((ext_vector_type(4))) float f32x4;
typedef unsigned short u16;

static constexpr int SEQ = 2048;
static constexpr int EMB = 1024;

// round-to-nearest-even fp32 -> bf16
DI u16 f2bf(float x) {
  uint32_t u = __float_as_uint(x);
  u += 0x7fffu + ((u >> 16) & 1u);
  return (u16)(u >> 16);
}

DI uint32_t pkbf(float a, float b) {
#if __has_builtin(__builtin_amdgcn_cvt_pk_bf16_f32)
  bf16x2 v = __builtin_amdgcn_cvt_pk_bf16_f32(a, b);
  return __builtin_bit_cast(uint32_t, v);
#else
  return (uint32_t)f2bf(a) | ((uint32_t)f2bf(b) << 16);
#endif
}

DI float fexp2(float x) {
#if __has_builtin(__builtin_amdgcn_exp2f)
  return __builtin_amdgcn_exp2f(x);
#else
  return exp2f(x);
#endif
}

DI f32x4 mfma16(short8 a, short8 b, f32x4 c) {
  return __builtin_amdgcn_mfma_f32_16x16x32_bf16(
      __builtin_bit_cast(bf16x8, a), __builtin_bit_cast(bf16x8, b), c, 0, 0, 0);
}

// async global->LDS, 16B per lane; LDS dest = wave-uniform base + lane*16
DI void g2l16(const u16* g, u16* l) {
  __builtin_amdgcn_global_load_lds(
      (const __attribute__((address_space(1))) unsigned int*)g,
      (__attribute__((address_space(3))) unsigned int*)l, 16, 0, 0);
}

// s_waitcnt imms: vm bits[3:0]+[15:14], exp [6:4], lgkm [11:8]
DI void wait_vm0() { __builtin_amdgcn_s_waitcnt(0x0F70); }   // vmcnt(0) only
DI void wait_vm6() { __builtin_amdgcn_s_waitcnt(0x0F76); }   // vmcnt(6) only
DI void wait_lgkm0() { __builtin_amdgcn_s_waitcnt(0xC07F); } // lgkmcnt(0) only
DI void memfence_c() { asm volatile("" ::: "memory"); }      // compiler-only fence

// ---------------- fused fp32 -> bf16 conversion (all 5 tensors) ----------------
__global__ __launch_bounds__(256) void cvt_all(
    const float* __restrict__ x,  const float* __restrict__ wq,
    const float* __restrict__ wk, const float* __restrict__ wv,
    const float* __restrict__ wo,
    u16* __restrict__ xb, u16* __restrict__ wqb, u16* __restrict__ wkb,
    u16* __restrict__ wvb, u16* __restrict__ wob) {
  const int bx = blockIdx.x;
  const float* s; u16* d; int off;
  if (bx < 4096) { s = x; d = xb; off = bx << 8; }
  else {
    const int r = bx - 4096, wsel = r >> 10;
    off = (r & 1023) << 8;
    s = wsel == 0 ? wq : (wsel == 1 ? wk : (wsel == 2 ? wv : wo));
    d = wsel == 0 ? wqb : (wsel == 1 ? wkb : (wsel == 2 ? wvb : wob));
  }
  const int i = off + threadIdx.x;
  float4 v = ((const float4*)s)[i];
  uint2 o;
  o.x = pkbf(v.x, v.y);
  o.y = pkbf(v.z, v.w);
  ((uint2*)d)[i] = o;
}

// ---------------- fused QKV projection: 8-phase 256x256 schedule -------------
// (verified round 5) C[4096 x 3072] = xb * W^T, K=1024. 192 blocks, 512 thr
// (8 waves = 2M x 4N), per-wave 128x64. BK=64. LDS 128 KB, XOR-8 swizzle.
// Counted vmcnt(6): 3 half-tiles stay in flight across raw s_barriers.
__global__ __launch_bounds__(512, 2) void gemm_qkv(
    const u16* __restrict__ xb,
    const u16* __restrict__ wqb, const u16* __restrict__ wkb,
    const u16* __restrict__ wvb,
    u16* __restrict__ Qb, u16* __restrict__ Kb, u16* __restrict__ Vt) {
  __shared__ u16 Al[2 * 256 * 64];      // 64 KB
  __shared__ u16 Bl[2 * 256 * 64];      // 64 KB
  const int t = threadIdx.x, L = t & 63, w = t >> 6;
  const int wm = (w >> 2) * 128, wn = (w & 3) * 64;
  const int r = L & 15, g = L >> 4;
  const int e = r & 7;
  const int ck0 = (g ^ e) * 8, ck1 = ((4 + g) ^ e) * 8;   // chunk for ks=0/1
  const int arow = wm >> 1;    // within-half j offset for A frag reads
  const int brow = wn >> 1;    // within-half j offset for B frag reads

  const int bx = blockIdx.x;
  const int m0 = (bx & 15) * 256;
  const int n0 = (bx >> 4) * 256;
  const int which = n0 >> 10;                 // 0:Q 1:K 2:V
  const u16* wsel = which == 0 ? wqb : (which == 1 ? wkb : wvb);
  const int nl0 = n0 & 1023;

  // staging constants: thread handles half-chunks c0=t (j 0..63), c1=t+512
  const int j0 = t >> 3, j1 = (t + 512) >> 3;
  const int sc0 = ((t & 7) ^ (j0 & 7)) * 8;
  const int sc1 = (((t + 512) & 7) ^ (j1 & 7)) * 8;
  const int ar0 = (j0 >> 6) * 128 + (j0 & 63);   // A half-0 row (h adds 64)
  const int ar1 = (j1 >> 6) * 128 + (j1 & 63);
  const int br0 = (j0 >> 5) * 64 + (j0 & 31);    // B half-0 row (h adds 32)
  const int br1 = (j1 >> 5) * 64 + (j1 & 31);
  const u16* As0 = xb + ((size_t)(m0 + ar0) << 10) + sc0;
  const u16* As1 = xb + ((size_t)(m0 + ar1) << 10) + sc1;
  const u16* Bs0 = wsel + ((size_t)(nl0 + br0) << 10) + sc0;
  const u16* Bs1 = wsel + ((size_t)(nl0 + br1) << 10) + sc1;

  f32x4 acc[8][4];
#pragma unroll
  for (int i = 0; i < 8; ++i)
#pragma unroll
    for (int j = 0; j < 4; ++j) acc[i][j] = f32x4{0.f, 0.f, 0.f, 0.f};
  short8 af[4][2], bn[4][2];

#define STG_A(kt, h)                                                          \
  { const size_t ko = (size_t)(kt) * 64 + (size_t)(h) * (64 << 10);           \
    u16* dd = Al + (((kt) & 1) << 14) + ((h) << 13);                          \
    g2l16(As0 + ko, dd + t * 8);                                              \
    g2l16(As1 + ko, dd + (t + 512) * 8); }
#define STG_B(kt, h)                                                          \
  { const size_t ko = (size_t)(kt) * 64 + (size_t)(h) * (32 << 10);           \
    u16* dd = Bl + (((kt) & 1) << 14) + ((h) << 13);                          \
    g2l16(Bs0 + ko, dd + t * 8);                                              \
    g2l16(Bs1 + ko, dd + (t + 512) * 8); }
#define LDA(bs, mh)                                                           \
  _Pragma("unroll") for (int mf = 0; mf < 4; ++mf) {                          \
    const u16* p = Al + ((bs) << 14) + ((mh) << 13) +                         \
                   (arow + mf * 16 + r) * 64;                                 \
    af[mf][0] = *(const short8*)(p + ck0);                                    \
    af[mf][1] = *(const short8*)(p + ck1); }
#define LDB(bs, nh)                                                           \
  _Pragma("unroll") for (int nf = 0; nf < 2; ++nf) {                          \
    const u16* p = Bl + ((bs) << 14) + ((nh) << 13) +                         \
                   (brow + nf * 16 + r) * 64;                                 \
    bn[(nh) * 2 + nf][0] = *(const short8*)(p + ck0);                         \
    bn[(nh) * 2 + nf][1] = *(const short8*)(p + ck1); }
#define MM(mh, nh)                                                            \
  _Pragma("unroll") for (int ks = 0; ks < 2; ++ks)                            \
  _Pragma("unroll") for (int mf = 0; mf < 4; ++mf)                            \
  _Pragma("unroll") for (int nf = 0; nf < 2; ++nf)                            \
    acc[(mh) * 4 + mf][(nh) * 2 + nf] = mfma16(                               \
        af[mf][ks], bn[(nh) * 2 + nf][ks], acc[(mh) * 4 + mf][(nh) * 2 + nf]);
#define PH_MID()                                                              \
  { memfence_c(); __builtin_amdgcn_s_barrier(); memfence_c();                 \
    wait_lgkm0(); __builtin_amdgcn_sched_barrier(0);                          \
    __builtin_amdgcn_s_setprio(1); }
#define PH_END()                                                              \
  { __builtin_amdgcn_s_setprio(0); __builtin_amdgcn_sched_barrier(0);         \
    memfence_c(); __builtin_amdgcn_s_barrier(); memfence_c(); }
// VMODE: 0 -> vmcnt(6), 1 -> vmcnt(0), 2 -> none
#define TILE(tt, S1, S2, VMODE)                                               \
  { const int bs_ = (tt) & 1;                                                 \
    LDA(bs_, 0); LDB(bs_, 0);                                                 \
    if (S1) STG_A((tt) + 1, 1);                                               \
    PH_MID(); MM(0, 0); PH_END();                                             \
    LDB(bs_, 1);                                                              \
    if (S2) STG_A((tt) + 2, 0);                                               \
    PH_MID(); MM(0, 1); PH_END();                                             \
    LDA(bs_, 1);                                                              \
    if (S2) STG_B((tt) + 2, 0);                                               \
    PH_MID(); MM(1, 1); PH_END();                                             \
    if (S2) STG_B((tt) + 2, 1);                                               \
    if ((VMODE) == 0) wait_vm6();                                             \
    else if ((VMODE) == 1) wait_vm0();                                        \
    PH_MID(); MM(1, 0); PH_END(); }

  // prologue: tiles 0 (all 4 halves) + tile 1 (3 halves); vmcnt(6) -> tile 0
  // fully landed (newest 3 halves may still be in flight)
  STG_A(0, 0); STG_B(0, 0); STG_B(0, 1); STG_A(0, 1);
  STG_A(1, 0); STG_B(1, 0); STG_B(1, 1);
  wait_vm6();
  memfence_c(); __builtin_amdgcn_s_barrier(); memfence_c();

  for (int tp = 0; tp < 7; ++tp) {      // tiles 0..13, buffer parity folded
    TILE(2 * tp, 1, 1, 0);
    TILE(2 * tp + 1, 1, 1, 0);
  }
  TILE(14, 1, 0, 1);                    // stage A-h1(15) only; drain vmcnt(0)
  TILE(15, 0, 0, 2);                    // no stages, no vmcnt

#undef STG_A
#undef STG_B
#undef LDA
#undef LDB
#undef MM
#undef PH_MID
#undef PH_END
#undef TILE

  // epilogue
  const int rl = (L >> 4) * 4, cl = L & 15;
  if (which < 2) {
    u16* outp = which == 0 ? Qb : Kb;
    // fold 1/sqrt(64) * log2(e) into Q (softmax runs in exp2 domain)
    const float sc = which == 0 ? 0.125f * 1.44269504089f : 1.0f;
#pragma unroll
    for (int mt = 0; mt < 8; ++mt) {
#pragma unroll
      for (int nt = 0; nt < 4; ++nt) {
        const int n = nl0 + wn + nt * 16 + cl;
#pragma unroll
        for (int rr = 0; rr < 4; ++rr) {
          const int m = m0 + wm + mt * 16 + rl + rr;
          outp[(size_t)m * EMB + n] = f2bf(acc[mt][nt][rr] * sc);
        }
      }
    }
  } else {
    // V: write transposed per head: Vt[(b*16+h)*64 + d][s]
#pragma unroll
    for (int mt = 0; mt < 8; ++mt) {
      const int mbase = m0 + wm + mt * 16 + rl;
      const int b = mbase >> 11, s = mbase & 2047;
#pragma unroll
      for (int nt = 0; nt < 4; ++nt) {
        const int n = nl0 + wn + nt * 16 + cl;
        const int h = n >> 6, d = n & 63;
        uint2 o;
        o.x = pkbf(acc[mt][nt][0], acc[mt][nt][1]);
        o.y = pkbf(acc[mt][nt][2], acc[mt][nt][3]);
        *(uint2*)(Vt + ((size_t)((b * 16 + h) * 64 + d) << 11) + s) = o;
      }
    }
  }
}

// ---------- flash attention (causal), in-block key-split, P in LDS ----------
// v10 = the R5-measured attn (2 jobs/block {15-base, base} = 17 tiles,
// 8 waves, wave-group key-split, double-buffered K/V, ones-MFMA l, in-block
// linear combine; LDS 96 KB, 1 block/CU) + T5 s_setprio(1/0) around the two
// MFMA clusters: waves drift phase inside a tile (no intra-tile barrier), so
// prioritizing MFMA-issuing waves over VALU/staging waves on the same SIMD
// is the m191 attn-positive case.
__global__ __launch_bounds__(512, 1) void attn(
    const u16* __restrict__ Qb, const u16* __restrict__ Kb,
    const u16* __restrict__ Vt, u16* __restrict__ Ob) {
  __shared__ __align__(16) u16 smem[49152];   // 96 KB
  u16* Kl = smem;                             // [2][128 key][64 d]  XOR-8 (32K)
  u16* Vl = smem + 16384;                     // [2][64 d][128 key]  XOR-8 (32K)
  u16* Pl = smem + 32768;                     // [2 gid][128 q][64 key] (32K); Q in Pl[0]
  float* Oc = (float*)smem;                   // combine: [128][68] f32 (over dead K/V)
  float* Lc = (float*)(smem + 17408);         // 128 f32 @ byte 34816

  const int t = threadIdx.x, w = t >> 6, gid = w >> 2, wl = w & 3;
  const int L = t & 63, g = L >> 4, cl = L & 15;
  const int gk = g ^ (cl & 3);          // swizzled low chunk bits for frag reads
  const int khi = (cl >> 2) & 1;        // swizzled high chunk bit
  const int qrow = wl * 16 + cl;

  // XCD-contiguous reindex: 4 heads per XCD -> K/V (2 MB) hot in 4 MB L2
  const int bi = (blockIdx.x & 7) * 32 + (blockIdx.x >> 3);   // bijective, 256
  const int bh = bi >> 3, base = bi & 7;
  const int b = bh >> 4, h = bh & 15;

  const u16* Kg = Kb + ((size_t)(b * SEQ) << 10) + h * 64;
  const u16* Vg = Vt + ((size_t)(bh * 64) << 11);

  const short8 ones = {0x3F80, 0x3F80, 0x3F80, 0x3F80,
                       0x3F80, 0x3F80, 0x3F80, 0x3F80};   // bf16 1.0 x8

  for (int job = 0; job < 2; ++job) {
    const int qt = job == 0 ? 15 - base : base;
    const int q0 = qt * 128;
    const u16* Qg = Qb + ((size_t)(b * SEQ + q0) << 10) + h * 64;

    // prologue: Q (1024 chunks) into Pl[0], K/V tile 0 into buf 0
#pragma unroll
    for (int i = 0; i < 2; ++i) {
      const int c = t + i * 512;
      const int row = c >> 3, col = ((c & 7) ^ (row & 7)) * 8;
      g2l16(Qg + ((size_t)row << 10) + col, Pl + c * 8);
      g2l16(Kg + ((size_t)row << 10) + col, Kl + c * 8);
      const int vr = c >> 4, vc = ((c & 15) ^ (vr & 7)) * 8;
      g2l16(Vg + ((size_t)vr << 11) + vc, Vl + c * 8);
    }
    wait_vm0();
    __syncthreads();

    // Q fragments for both q-halves (both wave-groups read the same rows)
    short8 qf[2][2];
#pragma unroll
    for (int qg = 0; qg < 2; ++qg)
#pragma unroll
      for (int ks = 0; ks < 2; ++ks)
        qf[qg][ks] = *(const short8*)(Pl + (qg * 64 + qrow) * 64 +
                                      ((ks ^ khi) * 4 + gk) * 8);
    __syncthreads();   // qf consumed before gid-0 P writes overwrite Pl[0]

    f32x4 oacc[2][4];
    f32x4 lacc[2] = {f32x4{0.f, 0.f, 0.f, 0.f}, f32x4{0.f, 0.f, 0.f, 0.f}};
#pragma unroll
    for (int qg = 0; qg < 2; ++qg)
#pragma unroll
      for (int dt = 0; dt < 4; ++dt) oacc[qg][dt] = f32x4{0.f, 0.f, 0.f, 0.f};

    u16* Pp = Pl + gid * 8192;
    const int kbase = gid * 64;

    for (int kt = 0; kt <= qt; ++kt) {
      const int cur = kt & 1;
      const u16* Klc = Kl + cur * 8192;
      const u16* Vlc = Vl + cur * 8192;
      if (kt < qt) {                      // prefetch tile kt+1 (async, no wait)
        const int k0n = (kt + 1) * 128;
        u16* Kln = Kl + (cur ^ 1) * 8192;
        u16* Vln = Vl + (cur ^ 1) * 8192;
#pragma unroll
        for (int i = 0; i < 2; ++i) {
          const int c = t + i * 512;
          const int row = c >> 3, col = ((c & 7) ^ (row & 7)) * 8;
          g2l16(Kg + ((size_t)(k0n + row) << 10) + col, Kln + c * 8);
          const int vr = c >> 4, vc = ((c & 15) ^ (vr & 7)) * 8;
          g2l16(Vg + ((size_t)vr << 11) + k0n + vc, Vln + c * 8);
        }
      }
      const bool diag = (kt == qt);
      const bool skip0 = diag && (gid == 1);   // qg0 fully masked for upper keys
      const int k064 = kt * 128 + kbase;

      // S^T: this group's 64 keys x 32 q (kf shared across both q-halves)
      f32x4 sacc[2][4];
#pragma unroll
      for (int qg = 0; qg < 2; ++qg)
#pragma unroll
        for (int mt = 0; mt < 4; ++mt) sacc[qg][mt] = f32x4{0.f, 0.f, 0.f, 0.f};
      __builtin_amdgcn_s_setprio(1);
#pragma unroll
      for (int ks = 0; ks < 2; ++ks)
#pragma unroll
        for (int mt = 0; mt < 4; ++mt) {
          const short8 kf = *(const short8*)(
              Klc + ((kbase + mt * 16 + cl) << 6) + ((ks ^ khi) * 4 + gk) * 8);
          if (!skip0) sacc[0][mt] = mfma16(kf, qf[0][ks], sacc[0][mt]);
          sacc[1][mt] = mfma16(kf, qf[1][ks], sacc[1][mt]);
        }
      __builtin_amdgcn_s_setprio(0);
      // softmax (exp2 domain), P into swizzled wave-private rows of Pp
#pragma unroll
      for (int qg = 0; qg < 2; ++qg) {
        if (qg == 0 && skip0) continue;
        const bool maskit = diag && ((qg == 0) ? (gid == 0) : (gid == 1));
        const int qglob = q0 + qg * 64 + qrow;
#pragma unroll
        for (int mt = 0; mt < 4; ++mt) {
          const int keyg = k064 + mt * 16 + g * 4;
          float p0 = fexp2(sacc[qg][mt][0]);
          float p1 = fexp2(sacc[qg][mt][1]);
          float p2 = fexp2(sacc[qg][mt][2]);
          float p3 = fexp2(sacc[qg][mt][3]);
          if (maskit) {
            if (keyg + 0 > qglob) p0 = 0.f;
            if (keyg + 1 > qglob) p1 = 0.f;
            if (keyg + 2 > qglob) p2 = 0.f;
            if (keyg + 3 > qglob) p3 = 0.f;
          }
          uint2 pk;
          pk.x = pkbf(p0, p1);
          pk.y = pkbf(p2, p3);
          const int pchunk = (mt * 2 + (g >> 1)) ^ (cl & 7);
          *(uint2*)(Pp + (qg * 64 + qrow) * 64 + pchunk * 8 + (g & 1) * 4) = pk;
        }
      }
      // O^T += V^T * P^T ; l += ones * P^T  (vf shared across q-halves)
      __builtin_amdgcn_s_setprio(1);
#pragma unroll
      for (int ks = 0; ks < 2; ++ks) {
        short8 pf0, pf1;
        if (!skip0)
          pf0 = *(const short8*)(Pp + qrow * 64 + ((ks ^ khi) * 4 + gk) * 8);
        pf1 = *(const short8*)(Pp + (64 + qrow) * 64 + ((ks ^ khi) * 4 + gk) * 8);
        if (!skip0) lacc[0] = mfma16(ones, pf0, lacc[0]);
        lacc[1] = mfma16(ones, pf1, lacc[1]);
#pragma unroll
        for (int dt = 0; dt < 4; ++dt) {
          const short8 vf = *(const short8*)(
              Vlc + ((dt * 16 + cl) << 7) + (kbase / 8 + (ks ^ khi) * 4 + gk) * 8);
          if (!skip0) oacc[0][dt] = mfma16(vf, pf0, oacc[0][dt]);
          oacc[1][dt] = mfma16(vf, pf1, oacc[1][dt]);
        }
      }
      __builtin_amdgcn_s_setprio(0);
      if (kt < qt) {
        wait_vm0();                       // prefetch landed (after compute!)
        __syncthreads();                  // one barrier per 128-key tile
      }
    }

    // ---- in-block combine (linear: O = O_A + O_B, l = l_A + l_B) ----
    __syncthreads();                      // all waves done reading K/V/P
    if (gid == 1) {
#pragma unroll
      for (int qg = 0; qg < 2; ++qg) {
#pragma unroll
        for (int dt = 0; dt < 4; ++dt)
          *(f32x4*)(Oc + (qg * 64 + qrow) * 68 + dt * 16 + g * 4) = oacc[qg][dt];
        if (g == 0) Lc[qg * 64 + qrow] = lacc[qg][0];
      }
    }
    __syncthreads();
    if (gid == 0) {
#pragma unroll
      for (int qg = 0; qg < 2; ++qg) {
        const float l = lacc[qg][0] + Lc[qg * 64 + qrow];
        const float inv = 1.f / l;
        const size_t qgl = (size_t)(b * SEQ + q0 + qg * 64 + qrow);
#pragma unroll
        for (int dt = 0; dt < 4; ++dt) {
          const f32x4 ov =
              *(const f32x4*)(Oc + (qg * 64 + qrow) * 68 + dt * 16 + g * 4);
          uint2 o;
          o.x = pkbf((oacc[qg][dt][0] + ov[0]) * inv,
                     (oacc[qg][dt][1] + ov[1]) * inv);
          o.y = pkbf((oacc[qg][dt][2] + ov[2]) * inv,
                     (oacc[qg][dt][3] + ov[3]) * inv);
          *(uint2*)(Ob + (qgl << 10) + h * 64 + dt * 16 + g * 4) = o;
        }
      }
    }
    __syncthreads();                      // combine reads done before next job's staging
  }
}

// ---------------- output projection: fp32 out = Ob * wo^T -------------------
// 128x64 tiles, BK=64 (half the barrier/drain count of BK=32), double-buffered.
// 64-col XOR swizzle identical to gemm_qkv's verified pattern: LDS chunk c of
// row j holds global chunk c^(j&7); frag read ck0=(g^e)*8, ck1=((4+g)^e)*8.
// LDS 48 KB -> 3 blocks/CU capacity; 512 blocks = clean 2/CU resident.
__global__ __launch_bounds__(256, 3) void gemm_out(const u16* __restrict__ Ab,
                                                   const u16* __restrict__ Wb,
                                                   float* __restrict__ out) {
  __shared__ u16 Al[2 * 128 * 64];      // 32 KB
  __shared__ u16 Bl[2 * 64 * 64];       // 16 KB
  const int t = threadIdx.x, L = t & 63, w = t >> 6;
  const int wm = (w >> 1) * 64, wn = (w & 1) * 32;
  const int r = L & 15, g = L >> 4;
  const int e = r & 7;
  const int ck0 = (g ^ e) * 8, ck1 = ((4 + g) ^ e) * 8;
  const int bx = blockIdx.x;
  const int m0 = (bx & 31) * 128;
  const int n0 = (bx >> 5) * 64;
  constexpr int AH = 128 * 64;          // elems per A half
  constexpr int BH = 64 * 64;           // elems per B half

  // staging: A chunks c = t + i*256 (i<4), B chunks c = t + i*256 (i<2);
  // row = c>>3, source col = ((c&7)^(row&7))*8 (XOR-8 within the 64-col row)
  const u16* Ap[4];
  const u16* Bp[2];
#pragma unroll
  for (int i = 0; i < 4; ++i) {
    const int c = t + i * 256, row = c >> 3, sc = ((c & 7) ^ (row & 7)) * 8;
    Ap[i] = Ab + ((size_t)(m0 + row) << 10) + sc;
  }
#pragma unroll
  for (int i = 0; i < 2; ++i) {
    const int c = t + i * 256, row = c >> 3, sc = ((c & 7) ^ (row & 7)) * 8;
    Bp[i] = Wb + ((size_t)(n0 + row) << 10) + sc;
  }

  f32x4 acc[4][2];
#pragma unroll
  for (int i = 0; i < 4; ++i)
#pragma unroll
    for (int j = 0; j < 2; ++j) acc[i][j] = f32x4{0.f, 0.f, 0.f, 0.f};

  // prologue: stage tile 0 into half 0
#pragma unroll
  for (int i = 0; i < 4; ++i) g2l16(Ap[i], Al + (t + i * 256) * 8);
#pragma unroll
  for (int i = 0; i < 2; ++i) g2l16(Bp[i], Bl + (t + i * 256) * 8);
  wait_vm0();
  __syncthreads();

  for (int ks = 0; ks < 16; ++ks) {
    const int cur = ks & 1;
    const u16* Alc = Al + cur * AH;
    const u16* Blc = Bl + cur * BH;
    if (ks < 15) {                        // prefetch tile ks+1 (async, no wait)
      const int k0 = (ks + 1) * 64;
      u16* Aln = Al + (cur ^ 1) * AH;
      u16* Bln = Bl + (cur ^ 1) * BH;
#pragma unroll
      for (int i = 0; i < 4; ++i) g2l16(Ap[i] + k0, Aln + (t + i * 256) * 8);
#pragma unroll
      for (int i = 0; i < 2; ++i) g2l16(Bp[i] + k0, Bln + (t + i * 256) * 8);
    }
    short8 af[4][2], bfr[2][2];
#pragma unroll
    for (int mt = 0; mt < 4; ++mt) {
      const u16* p = Alc + (wm + mt * 16 + r) * 64;
      af[mt][0] = *(const short8*)(p + ck0);
      af[mt][1] = *(const short8*)(p + ck1);
    }
#pragma unroll
    for (int nt = 0; nt < 2; ++nt) {
      const u16* p = Blc + (wn + nt * 16 + r) * 64;
      bfr[nt][0] = *(const short8*)(p + ck0);
      bfr[nt][1] = *(const short8*)(p + ck1);
    }
#pragma unroll
    for (int kk = 0; kk < 2; ++kk)
#pragma unroll
      for (int mt = 0; mt < 4; ++mt)
#pragma unroll
        for (int nt = 0; nt < 2; ++nt)
          acc[mt][nt] = mfma16(af[mt][kk], bfr[nt][kk], acc[mt][nt]);
    if (ks < 15) {
      wait_vm0();                         // prefetch landed (after compute!)
      __syncthreads();                    // one barrier per K-tile (16 total)
    }
  }

  const int rl = (L >> 4) * 4, cl = L & 15;
#pragma unroll
  for (int mt = 0; mt < 4; ++mt)
#pragma unroll
    for (int nt = 0; nt < 2; ++nt) {
      const int n = n0 + wn + nt * 16 + cl;
#pragma unroll
      for (int rr = 0; rr < 4; ++rr) {
        const int m = m0 + wm + mt * 16 + rl + rr;
        out[(size_t)m * EMB + n] = acc[mt][nt][rr];
      }
    }
}

// ---------------- launch ----------------
extern "C" void kernel_launch(void* const* d_in, const int* in_sizes, int n_in,
                              void* d_out, int out_size, void* d_ws, size_t ws_size,
                              hipStream_t stream) {
  const float* x  = (const float*)d_in[0];
  const float* wq = (const float*)d_in[1];
  const float* wk = (const float*)d_in[2];
  const float* wv = (const float*)d_in[3];
  const float* wo = (const float*)d_in[4];
  float* out = (float*)d_out;

  char* ws = (char*)d_ws;
  u16* xb  = (u16*)(ws);                          // 8 MB  [4096][1024]
  u16* wqb = (u16*)(ws + ((size_t)8  << 20));     // 2 MB
  u16* wkb = (u16*)(ws + ((size_t)10 << 20));     // 2 MB
  u16* wvb = (u16*)(ws + ((size_t)12 << 20));     // 2 MB
  u16* wob = (u16*)(ws + ((size_t)14 << 20));     // 2 MB
  u16* Qb  = (u16*)(ws + ((size_t)16 << 20));     // 8 MB  pre-scaled by 0.125*log2e
  u16* Kb  = (u16*)(ws + ((size_t)24 << 20));     // 8 MB
  u16* Vt  = (u16*)(ws + ((size_t)32 << 20));     // 8 MB  [32*64][2048] transposed
  u16* Ob  = (u16*)(ws + ((size_t)40 << 20));     // 8 MB

  cvt_all<<<8192, 256, 0, stream>>>(x, wq, wk, wv, wo, xb, wqb, wkb, wvb, wob);
  gemm_qkv<<<192, 512, 0, stream>>>(xb, wqb, wkb, wvb, Qb, Kb, Vt);
  attn<<<256, 512, 0, stream>>>(Qb, Kb, Vt, Ob);
  gemm_out<<<512, 256, 0, stream>>>(Ob, wob, out);
}